// Round 1
// baseline (541.905 us; speedup 1.0000x reference)
//
#include <hip/hip_runtime.h>
#include <stdint.h>

typedef unsigned int u32;
typedef unsigned long long u64;

#define BATCH 16
#define NANCH 25200
#define NCLS 80
#define ROWF 85
#define MAXC 1000
#define CONF_T 0.25f
#define IOU_T 0.45f
#define EPS_F 1e-7f
#define APT (NANCH/4)   /* anchor-quads per batch = 6300 */

// IoU exactly as the numpy/JAX reference computes it (no FMA contraction:
// keep inter's rounding separate from the union subtraction).
__device__ __forceinline__ float iou_ref(float4 a, float4 b) {
#pragma clang fp contract(off)
  float ai = (a.z - a.x) * (a.w - a.y);
  float aj = (b.z - b.x) * (b.w - b.y);
  float ltx = fmaxf(a.x, b.x), lty = fmaxf(a.y, b.y);
  float rbx = fminf(a.z, b.z), rby = fminf(a.w, b.w);
  float wx = fmaxf(rbx - ltx, 0.0f), wy = fmaxf(rby - lty, 0.0f);
  float inter = wx * wy;
  return inter / (ai + aj - inter + EPS_F);
}

// K1: score all anchors, emit sortable 64-bit keys + fused coarse histogram.
// key = ordered(score)<<32 | (32767-n)<<7 | cls  (desc score, ties asc index)
__global__ __launch_bounds__(256) void k1_score(const float* __restrict__ pred,
                                                u64* __restrict__ keys,
                                                u32* __restrict__ hist) {
  __shared__ u32 lh[512];
  int tid = threadIdx.x;
  for (int i = tid; i < 512; i += 256) lh[i] = 0;
  __syncthreads();
  int t = blockIdx.x * 256 + tid;
  int b0 = (blockIdx.x * 256) / APT;
  if (t < BATCH * APT) {
    int b = t / APT;
    int n0 = (t % APT) * 4;
    const float4* src = (const float4*)(pred + ((size_t)b * NANCH + n0) * ROWF);
    float obj[4] = {0, 0, 0, 0};
    float best[4] = {-1e30f, -1e30f, -1e30f, -1e30f};
    int bidx[4] = {0, 0, 0, 0};
#pragma unroll
    for (int v = 0; v < ROWF; ++v) {
      float4 q = src[v];
      float vals[4] = {q.x, q.y, q.z, q.w};
#pragma unroll
      for (int k2 = 0; k2 < 4; ++k2) {
        const int e = 4 * v + k2;
        const int a = e / ROWF;
        const int f = e % ROWF;
        float val = vals[k2];
        if (f == 4) obj[a] = val;
        else if (f >= 5) {
          float s = val * obj[a];            // exact same mul as reference
          if (s > best[a]) { best[a] = s; bidx[a] = f - 5; }  // first-max argmax
        }
      }
    }
    int slot = b - b0;
#pragma unroll
    for (int a = 0; a < 4; ++a) {
      int n = n0 + a;
      float conf = best[a];
      bool valid = (obj[a] > CONF_T) && (conf > CONF_T);
      u32 hi;
      if (valid) hi = __float_as_uint(conf) | 0x80000000u;   // ordered-float, >0x80000000
      else hi = ((u32)n * 2654435761u) >> 1;                 // spread, <0x80000000
      u32 lo = ((u32)(32767 - n) << 7) | (u32)bidx[a];
      keys[(size_t)b * NANCH + n] = ((u64)hi << 32) | lo;
      atomicAdd(&lh[slot * 256 + (hi >> 24)], 1u);
    }
  }
  __syncthreads();
  for (int i = tid; i < 512; i += 256) {
    u32 v = lh[i];
    int bb = b0 + (i >> 8);
    if (v && bb < BATCH) atomicAdd(&hist[bb * 256 + (i & 255)], v);
  }
}

// K2: per-batch exact top-1000 (radix select on high 32 bits, compact,
// bitonic sort 2048 in LDS), gather boxes, build offset boxes.
__global__ __launch_bounds__(1024) void k2_select(const float* __restrict__ pred,
                                                  const u64* __restrict__ keys,
                                                  const u32* __restrict__ hist,
                                                  float* __restrict__ selbox,
                                                  float* __restrict__ offbox,
                                                  float* __restrict__ selconf,
                                                  float* __restrict__ selcls,
                                                  u32* __restrict__ selvalid) {
  int b = blockIdx.x;
  int tid = threadIdx.x;
  __shared__ u32 sh_hist[256];
  __shared__ u32 sh_prefix;
  __shared__ int sh_rank;
  __shared__ u32 scount;
  __shared__ u64 skey[2048];

  if (tid == 0) {                  // round 0 from K1's precomputed histogram
    int rank = MAXC, cum = 0, sel = 0;
    for (int i = 255; i >= 0; --i) {
      int c = (int)hist[b * 256 + i];
      if (cum + c >= rank) { sel = i; break; }
      cum += c;
    }
    sh_prefix = (u32)sel;
    sh_rank = rank - cum;
  }
  __syncthreads();
  u32 prefix = sh_prefix;
  const u32* hik = (const u32*)(keys + (size_t)b * NANCH);  // [2i+1] = high word
  for (int r = 1; r <= 3; ++r) {
    int shift = 24 - 8 * r;
    if (tid < 256) sh_hist[tid] = 0;
    __syncthreads();
    for (int i = tid; i < NANCH; i += 1024) {
      u32 hi = hik[2 * i + 1];
      if ((hi >> (shift + 8)) == prefix)
        atomicAdd(&sh_hist[(hi >> shift) & 255u], 1u);
    }
    __syncthreads();
    if (tid == 0) {
      int rank = sh_rank, cum = 0, sel = 0;
      for (int i = 255; i >= 0; --i) {
        int c = (int)sh_hist[i];
        if (cum + c >= rank) { sel = i; break; }
        cum += c;
      }
      sh_prefix = (prefix << 8) | (u32)sel;
      sh_rank = rank - cum;
    }
    __syncthreads();
    prefix = sh_prefix;
  }
  u32 Cstar = prefix;

  if (tid == 0) scount = 0;
  skey[tid] = ~0ull;
  skey[tid + 1024] = ~0ull;
  __syncthreads();
  for (int i = tid; i < NANCH; i += 1024) {
    u64 k = keys[(size_t)b * NANCH + i];
    if ((u32)(k >> 32) >= Cstar) {
      u32 p = atomicAdd(&scount, 1u);
      if (p < 2048) skey[p] = ~k;      // sort ascending on ~key == descending key
    }
  }
  __syncthreads();
  for (u32 kk = 2; kk <= 2048; kk <<= 1) {
    for (u32 j = kk >> 1; j > 0; j >>= 1) {
      for (int idx = tid; idx < 2048; idx += 1024) {
        u32 ixj = (u32)idx ^ j;
        if (ixj > (u32)idx) {
          u64 a = skey[idx], c2 = skey[ixj];
          bool up = ((idx & kk) == 0);
          if (up ? (a > c2) : (a < c2)) { skey[idx] = c2; skey[ixj] = a; }
        }
      }
      __syncthreads();
    }
  }
  if (tid < MAXC) {
    u64 k = ~skey[tid];
    u32 hi = (u32)(k >> 32);
    u32 lo = (u32)k;
    u32 n = 32767u - (lo >> 7);
    u32 ci = lo & 127u;
    bool valid = hi > 0x80000000u;
    float conf = valid ? __uint_as_float(hi & 0x7FFFFFFFu) : 0.0f;
    const float* pr = pred + ((size_t)b * NANCH + n) * ROWF;
    float x = pr[0], y = pr[1], w = pr[2], h = pr[3];
    float x1 = x - w * 0.5f, y1 = y - h * 0.5f;
    float x2 = x + w * 0.5f, y2 = y + h * 0.5f;
    float cf = (float)ci;
    float off = cf * 4096.0f;
    int o4 = (b * MAXC + tid) * 4;
    selbox[o4 + 0] = x1; selbox[o4 + 1] = y1; selbox[o4 + 2] = x2; selbox[o4 + 3] = y2;
    offbox[o4 + 0] = x1 + off; offbox[o4 + 1] = y1 + off;
    offbox[o4 + 2] = x2 + off; offbox[o4 + 3] = y2 + off;
    selconf[b * MAXC + tid] = conf;
    selcls[b * MAXC + tid] = cf;
    selvalid[b * MAXC + tid] = valid ? 1u : 0u;
  }
}

// K3: full suppression bit-matrix, one wave per row, ballot -> u64 words.
__global__ __launch_bounds__(256) void k3_masks(const float4* __restrict__ offbox4,
                                                u64* __restrict__ masks) {
  int wid = blockIdx.x * 4 + (threadIdx.x >> 6);
  int lane = threadIdx.x & 63;
  int b = wid / MAXC;
  int row = wid % MAXC;
  float4 bi = offbox4[b * MAXC + row];
  u64 myword = 0;
  for (int w = 0; w < 16; ++w) {
    int j = w * 64 + lane;
    int jc = (j < MAXC) ? j : 0;
    float4 bj = offbox4[b * MAXC + jc];
    float iou = iou_ref(bi, bj);
    bool bit = (iou > IOU_T) && (j > row) && (j < MAXC);
    u64 bal = __ballot(bit ? 1 : 0);
    if (lane == w) myword = bal;
  }
  if (lane < 16) masks[((size_t)b * MAXC + row) * 16 + lane] = myword;
}

// K3b: transposed 64x64 diagonal blocks (lane l holds column l: bit t set if
// row 64c+t suppresses row 64c+l). IoU is bitwise-symmetric, so compute directly.
__global__ __launch_bounds__(256) void k3b_diag(const float4* __restrict__ offbox4,
                                                u64* __restrict__ diagT) {
  int wid = blockIdx.x * 4 + (threadIdx.x >> 6);   // 0..255 = b*16+c
  int lane = threadIdx.x & 63;
  int b = wid / 16;
  int c = wid % 16;
  int row = c * 64 + lane;
  float4 bi = (row < MAXC) ? offbox4[b * MAXC + row] : make_float4(0, 0, 0, 0);
  u64 word = 0;
  for (int t = 0; t < 64; ++t) {
    int j = c * 64 + t;
    float4 bj = (j < MAXC) ? offbox4[b * MAXC + j] : make_float4(0, 0, 0, 0);
    float iou = iou_ref(bi, bj);
    bool bit = (iou > IOU_T) && (lane > t) && (row < MAXC);
    word |= ((u64)(bit ? 1 : 0)) << t;
  }
  diagT[((size_t)b * 16 + c) * 64 + lane] = word;
}

// K4: serial greedy scan (wave 0 per batch), ballot-chain over 64-row chunks,
// register-ring prefetch of off-diagonal mask rows; then write outputs.
__global__ __launch_bounds__(256) void k4_scan(const u64* __restrict__ masks,
                                               const u64* __restrict__ diagT,
                                               const u32* __restrict__ selvalid,
                                               const float* __restrict__ selbox,
                                               const float* __restrict__ selconf,
                                               const float* __restrict__ selcls,
                                               float* __restrict__ out) {
  int b = blockIdx.x;
  int tid = threadIdx.x;
  __shared__ u64 keepw[16];
  if (tid < 64) {
    int lane = tid;
    u64 kw = 0;
    for (int w = 0; w < 16; ++w) {
      int e = w * 64 + lane;
      u32 v = (e < MAXC) ? selvalid[b * MAXC + e] : 0u;
      u64 bal = __ballot(v != 0u ? 1 : 0);
      if (lane == w) kw = bal;
    }
    const u64* mrow = masks + (size_t)b * MAXC * 16;
    u64 ring[16];
#pragma unroll
    for (int s = 0; s < 16; ++s)
      ring[s] = (lane < 16) ? mrow[s * 16 + lane] : 0ull;
    for (int c = 0; c < 16; ++c) {
      u64 wc = __shfl(kw, c);
      u64 dT = diagT[((size_t)b * 16 + c) * 64 + lane];
      u32 alive = (u32)(wc >> lane) & 1u;
#pragma unroll
      for (int t = 0; t < 64; ++t) {       // greedy order inside the chunk
        u64 cur = __ballot(alive != 0u ? 1 : 0);
        u32 sup = (u32)(cur >> t) & (u32)(dT >> t) & 1u;
        alive &= (sup ^ 1u);
      }
      u64 fin = __ballot(alive != 0u ? 1 : 0);
      if (lane == c) kw = fin;
      int p = c * 64;
      for (int tb = 0; tb < 4; ++tb) {
#pragma unroll
        for (int u = 0; u < 16; ++u) {
          int i = p + tb * 16 + u;
          u64 m = ring[u];
          int nxt = i + 16;
          ring[u] = (nxt < MAXC && lane < 16) ? mrow[(size_t)nxt * 16 + lane] : 0ull;
          u64 kept = (fin >> (tb * 16 + u)) & 1ull;
          if (lane != c) kw &= ~(kept ? m : 0ull);   // word c already final
        }
      }
    }
    if (lane < 16) keepw[lane] = kw;
  }
  __syncthreads();
  for (int e = tid; e < MAXC; e += 256) {
    bool kept = ((keepw[e >> 6] >> (e & 63)) & 1ull) != 0ull;
    size_t o = (size_t)b * MAXC + e;
    float b0 = selbox[o * 4 + 0], b1 = selbox[o * 4 + 1];
    float b2 = selbox[o * 4 + 2], b3 = selbox[o * 4 + 3];
    float cf = selconf[o], cl = selcls[o];
    float* orow = out + o * 6;
    orow[0] = kept ? b0 : 0.0f;
    orow[1] = kept ? b1 : 0.0f;
    orow[2] = kept ? b2 : 0.0f;
    orow[3] = kept ? b3 : 0.0f;
    orow[4] = kept ? cf : 0.0f;
    orow[5] = kept ? cl : 0.0f;
    out[(size_t)BATCH * MAXC * 6 + o] = kept ? 1.0f : 0.0f;
  }
}

extern "C" void kernel_launch(void* const* d_in, const int* in_sizes, int n_in,
                              void* d_out, int out_size, void* d_ws, size_t ws_size,
                              hipStream_t stream) {
  const float* pred = (const float*)d_in[0];
  float* out = (float*)d_out;
  char* ws = (char*)d_ws;
  size_t off = 0;
  auto alloc = [&](size_t bytes) -> void* {
    void* p = ws + off;
    off = (off + bytes + 255) & ~(size_t)255;
    return p;
  };
  u64* keys     = (u64*)alloc((size_t)BATCH * NANCH * 8);
  u32* hist     = (u32*)alloc((size_t)BATCH * 256 * 4);
  float* selbox = (float*)alloc((size_t)BATCH * MAXC * 4 * 4);
  float* offbox = (float*)alloc((size_t)BATCH * MAXC * 4 * 4);
  float* selconf= (float*)alloc((size_t)BATCH * MAXC * 4);
  float* selcls = (float*)alloc((size_t)BATCH * MAXC * 4);
  u32* selvalid = (u32*)alloc((size_t)BATCH * MAXC * 4);
  u64* masks    = (u64*)alloc((size_t)BATCH * MAXC * 16 * 8);
  u64* diagT    = (u64*)alloc((size_t)BATCH * 16 * 64 * 8);
  (void)ws_size; (void)in_sizes; (void)n_in; (void)out_size;

  hipMemsetAsync(hist, 0, (size_t)BATCH * 256 * 4, stream);

  int k1_blocks = (BATCH * APT + 255) / 256;   // 394
  k1_score<<<k1_blocks, 256, 0, stream>>>(pred, keys, hist);
  k2_select<<<BATCH, 1024, 0, stream>>>(pred, keys, hist, selbox, offbox,
                                        selconf, selcls, selvalid);
  k3_masks<<<(BATCH * MAXC) / 4, 256, 0, stream>>>((const float4*)offbox, masks);
  k3b_diag<<<(BATCH * 16) / 4, 256, 0, stream>>>((const float4*)offbox, diagT);
  k4_scan<<<BATCH, 256, 0, stream>>>(masks, diagT, selvalid, selbox, selconf,
                                     selcls, out);
}

// Round 2
// 280.622 us; speedup vs baseline: 1.9311x; 1.9311x over previous
//
#include <hip/hip_runtime.h>
#include <stdint.h>

typedef unsigned int u32;
typedef unsigned long long u64;

#define BATCH 16
#define NANCH 25200
#define NCLS 80
#define ROWF 85
#define MAXC 1000
#define CONF_T 0.25f
#define IOU_T 0.45f
#define EPS_F 1e-7f
#define APT (NANCH/4)   /* anchor-quads per batch = 6300 */

// IoU exactly as the numpy/JAX reference computes it (no FMA contraction:
// keep inter's rounding separate from the union subtraction).
__device__ __forceinline__ float iou_ref(float4 a, float4 b) {
#pragma clang fp contract(off)
  float ai = (a.z - a.x) * (a.w - a.y);
  float aj = (b.z - b.x) * (b.w - b.y);
  float ltx = fmaxf(a.x, b.x), lty = fmaxf(a.y, b.y);
  float rbx = fminf(a.z, b.z), rby = fminf(a.w, b.w);
  float wx = fmaxf(rbx - ltx, 0.0f), wy = fmaxf(rby - lty, 0.0f);
  float inter = wx * wy;
  return inter / (ai + aj - inter + EPS_F);
}

// K1: score all anchors, emit sortable 64-bit keys + fused coarse histogram.
// key = ordered(score)<<32 | (32767-n)<<7 | cls  (desc score, ties asc index)
__global__ __launch_bounds__(256) void k1_score(const float* __restrict__ pred,
                                                u64* __restrict__ keys,
                                                u32* __restrict__ hist) {
  __shared__ u32 lh[512];
  int tid = threadIdx.x;
  for (int i = tid; i < 512; i += 256) lh[i] = 0;
  __syncthreads();
  int t = blockIdx.x * 256 + tid;
  int b0 = (blockIdx.x * 256) / APT;
  if (t < BATCH * APT) {
    int b = t / APT;
    int n0 = (t % APT) * 4;
    const float4* src = (const float4*)(pred + ((size_t)b * NANCH + n0) * ROWF);
    float obj[4] = {0, 0, 0, 0};
    float best[4] = {-1e30f, -1e30f, -1e30f, -1e30f};
    int bidx[4] = {0, 0, 0, 0};
#pragma unroll
    for (int v = 0; v < ROWF; ++v) {
      float4 q = src[v];
      float vals[4] = {q.x, q.y, q.z, q.w};
#pragma unroll
      for (int k2 = 0; k2 < 4; ++k2) {
        const int e = 4 * v + k2;
        const int a = e / ROWF;
        const int f = e % ROWF;
        float val = vals[k2];
        if (f == 4) obj[a] = val;
        else if (f >= 5) {
          float s = val * obj[a];            // exact same mul as reference
          if (s > best[a]) { best[a] = s; bidx[a] = f - 5; }  // first-max argmax
        }
      }
    }
    int slot = b - b0;
#pragma unroll
    for (int a = 0; a < 4; ++a) {
      int n = n0 + a;
      float conf = best[a];
      bool valid = (obj[a] > CONF_T) && (conf > CONF_T);
      u32 hi;
      if (valid) hi = __float_as_uint(conf) | 0x80000000u;   // ordered-float, >0x80000000
      else hi = ((u32)n * 2654435761u) >> 1;                 // spread, <0x80000000
      u32 lo = ((u32)(32767 - n) << 7) | (u32)bidx[a];
      keys[(size_t)b * NANCH + n] = ((u64)hi << 32) | lo;
      atomicAdd(&lh[slot * 256 + (hi >> 24)], 1u);
    }
  }
  __syncthreads();
  for (int i = tid; i < 512; i += 256) {
    u32 v = lh[i];
    int bb = b0 + (i >> 8);
    if (v && bb < BATCH) atomicAdd(&hist[bb * 256 + (i & 255)], v);
  }
}

// K2: per-batch exact top-1000 (radix select on high 32 bits, compact,
// bitonic sort 2048 in LDS), gather boxes, build offset boxes.
// Selection of the pivot bin is done by wave 0 via shfl suffix-scan
// (the R1 serial tid==0 scans were ~120k dependent-LDS-latency cycles).
__global__ __launch_bounds__(1024) void k2_select(const float* __restrict__ pred,
                                                  const u64* __restrict__ keys,
                                                  const u32* __restrict__ hist,
                                                  float* __restrict__ selbox,
                                                  float* __restrict__ offbox,
                                                  float* __restrict__ selconf,
                                                  float* __restrict__ selcls,
                                                  u32* __restrict__ selvalid) {
  int b = blockIdx.x;
  int tid = threadIdx.x;
  __shared__ u32 h[256];
  __shared__ u32 sh_sel;
  __shared__ int sh_rank;
  __shared__ u32 scount;
  __shared__ u64 skey[2048];

  const u32* hik = (const u32*)(keys + (size_t)b * NANCH);  // [2i+1] = high word
  u32 prefix = 0;
  for (int r = 0; r < 4; ++r) {
    if (r == 0) {
      if (tid < 256) h[tid] = hist[b * 256 + tid];
    } else {
      if (tid < 256) h[tid] = 0;
      __syncthreads();
      int shift = 24 - 8 * r;
      for (int i = tid; i < NANCH; i += 1024) {
        u32 hi = hik[2 * i + 1];
        if ((hi >> (shift + 8)) == prefix)
          atomicAdd(&h[(hi >> shift) & 255u], 1u);
      }
    }
    __syncthreads();
    if (tid < 64) {   // wave-0 parallel suffix-scan select, no barriers inside
      int l = tid;
      u32 a0 = h[4 * l + 0], a1 = h[4 * l + 1], a2 = h[4 * l + 2], a3 = h[4 * l + 3];
      u32 lane_sum = a0 + a1 + a2 + a3;
      u32 suf = lane_sum;
#pragma unroll
      for (int off = 1; off < 64; off <<= 1) {
        u32 tv = __shfl_down(suf, off);
        if (l + off < 64) suf += tv;
      }
      int rank = (r == 0) ? MAXC : sh_rank;
      u32 e3 = suf - lane_sum; u32 i3 = e3 + a3;
      u32 e2 = i3;             u32 i2 = e2 + a2;
      u32 e1 = i2;             u32 i1 = e1 + a1;
      u32 e0 = i1;             u32 i0 = e0 + a0;
      if ((int)i3 >= rank && (int)e3 < rank) { sh_sel = 4u * l + 3u; sh_rank = rank - (int)e3; }
      if ((int)i2 >= rank && (int)e2 < rank) { sh_sel = 4u * l + 2u; sh_rank = rank - (int)e2; }
      if ((int)i1 >= rank && (int)e1 < rank) { sh_sel = 4u * l + 1u; sh_rank = rank - (int)e1; }
      if ((int)i0 >= rank && (int)e0 < rank) { sh_sel = 4u * l + 0u; sh_rank = rank - (int)e0; }
    }
    __syncthreads();
    prefix = (r == 0) ? sh_sel : ((prefix << 8) | sh_sel);
  }
  u32 Cstar = prefix;

  if (tid == 0) scount = 0;
  skey[tid] = ~0ull;
  skey[tid + 1024] = ~0ull;
  __syncthreads();
  for (int i = tid; i < NANCH; i += 1024) {
    u64 k = keys[(size_t)b * NANCH + i];
    if ((u32)(k >> 32) >= Cstar) {
      u32 p = atomicAdd(&scount, 1u);
      if (p < 2048) skey[p] = ~k;      // sort ascending on ~key == descending key
    }
  }
  __syncthreads();
  for (u32 kk = 2; kk <= 2048; kk <<= 1) {
    for (u32 j = kk >> 1; j > 0; j >>= 1) {
      for (int idx = tid; idx < 2048; idx += 1024) {
        u32 ixj = (u32)idx ^ j;
        if (ixj > (u32)idx) {
          u64 a = skey[idx], c2 = skey[ixj];
          bool up = ((idx & kk) == 0);
          if (up ? (a > c2) : (a < c2)) { skey[idx] = c2; skey[ixj] = a; }
        }
      }
      __syncthreads();
    }
  }
  if (tid < MAXC) {
    u64 k = ~skey[tid];
    u32 hi = (u32)(k >> 32);
    u32 lo = (u32)k;
    u32 n = 32767u - (lo >> 7);
    u32 ci = lo & 127u;
    bool valid = hi > 0x80000000u;
    float conf = valid ? __uint_as_float(hi & 0x7FFFFFFFu) : 0.0f;
    const float* pr = pred + ((size_t)b * NANCH + n) * ROWF;
    float x = pr[0], y = pr[1], w = pr[2], h2 = pr[3];
    float x1 = x - w * 0.5f, y1 = y - h2 * 0.5f;
    float x2 = x + w * 0.5f, y2 = y + h2 * 0.5f;
    float cf = (float)ci;
    float off = cf * 4096.0f;
    int o4 = (b * MAXC + tid) * 4;
    selbox[o4 + 0] = x1; selbox[o4 + 1] = y1; selbox[o4 + 2] = x2; selbox[o4 + 3] = y2;
    offbox[o4 + 0] = x1 + off; offbox[o4 + 1] = y1 + off;
    offbox[o4 + 2] = x2 + off; offbox[o4 + 3] = y2 + off;
    selconf[b * MAXC + tid] = conf;
    selcls[b * MAXC + tid] = cf;
    selvalid[b * MAXC + tid] = valid ? 1u : 0u;
  }
}

// K3: TRANSPOSED suppression bit-matrix Dt. Row i (victim), bit j set iff
// iou(j,i) > T and j < i. One wave per row; ballot -> u64 words.
__global__ __launch_bounds__(256) void k3_dt(const float4* __restrict__ offbox4,
                                             u64* __restrict__ dt) {
  int wid = blockIdx.x * 4 + (threadIdx.x >> 6);   // b*MAXC + i
  int lane = threadIdx.x & 63;
  int b = wid / MAXC;
  int i = wid % MAXC;
  float4 bi = offbox4[b * MAXC + i];
  u64 myword = 0;
  for (int w = 0; w < 16; ++w) {
    int j = w * 64 + lane;
    int jc = (j < MAXC) ? j : 0;
    float4 bj = offbox4[b * MAXC + jc];
    float iou = iou_ref(bi, bj);
    bool bit = (iou > IOU_T) && (j < i);            // j<i implies j<MAXC
    u64 bal = __ballot(bit ? 1 : 0);
    if (lane == w) myword = bal;
  }
  if (lane < 16) dt[((size_t)b * MAXC + i) * 16 + lane] = myword;
}

// K4: Jacobi fixed-point of keep[i] = valid[i] & ~OR_{j<i}(keep[j]&D[j,i]).
// Unique fixed point == greedy NMS result; converges in max-chain-depth
// passes (~2-5 for random boxes). Thread i holds Dt row in registers;
// keep vector (16 u64) lives in LDS, rebuilt per pass via per-wave ballots.
__global__ __launch_bounds__(1024) void k4_jacobi(const u64* __restrict__ dt,
                                                  const u32* __restrict__ selvalid,
                                                  const float* __restrict__ selbox,
                                                  const float* __restrict__ selconf,
                                                  const float* __restrict__ selcls,
                                                  float* __restrict__ out) {
  int b = blockIdx.x;
  int tid = threadIdx.x;
  int wv = tid >> 6, lane = tid & 63;
  __shared__ u64 keepv[16];
  __shared__ u32 changed;
  bool valid = false;
  u64 dtr[16];
  if (tid < MAXC) {
    valid = selvalid[b * MAXC + tid] != 0u;
#pragma unroll
    for (int w = 0; w < 16; ++w) dtr[w] = dt[((size_t)b * MAXC + tid) * 16 + w];
  } else {
#pragma unroll
    for (int w = 0; w < 16; ++w) dtr[w] = 0ull;
  }
  u64 bal0 = __ballot(valid ? 1 : 0);
  if (tid == 0) changed = 0;
  if (lane == 0) keepv[wv] = bal0;
  __syncthreads();
  for (int pass = 0; pass < MAXC; ++pass) {
    u64 kv[16];
#pragma unroll
    for (int w = 0; w < 16; ++w) kv[w] = keepv[w];
    u64 s = 0;
#pragma unroll
    for (int w = 0; w < 16; ++w) s |= dtr[w] & kv[w];
    bool nk = valid && (s == 0ull);
    u64 bal = __ballot(nk ? 1 : 0);
    __syncthreads();                       // A: all keepv reads done
    if (lane == 0 && bal != kv[wv]) { keepv[wv] = bal; atomicOr(&changed, 1u); }
    __syncthreads();                       // B: writes visible
    u32 ch = changed;
    __syncthreads();                       // C: all read ch before reset
    if (tid == 0) changed = 0;
    if (!ch) break;                        // ch uniform -> uniform exit
  }
  // keepv stable (last pass wrote nothing), barriers already passed.
  if (tid < MAXC) {
    bool kept = ((keepv[wv] >> lane) & 1ull) != 0ull;
    size_t o = (size_t)b * MAXC + tid;
    const float4* sb4 = (const float4*)selbox;
    float4 bx = sb4[o];
    float cf = selconf[o], cl = selcls[o];
    float* orow = out + o * 6;
    orow[0] = kept ? bx.x : 0.0f;
    orow[1] = kept ? bx.y : 0.0f;
    orow[2] = kept ? bx.z : 0.0f;
    orow[3] = kept ? bx.w : 0.0f;
    orow[4] = kept ? cf : 0.0f;
    orow[5] = kept ? cl : 0.0f;
    out[(size_t)BATCH * MAXC * 6 + o] = kept ? 1.0f : 0.0f;
  }
}

extern "C" void kernel_launch(void* const* d_in, const int* in_sizes, int n_in,
                              void* d_out, int out_size, void* d_ws, size_t ws_size,
                              hipStream_t stream) {
  const float* pred = (const float*)d_in[0];
  float* out = (float*)d_out;
  char* ws = (char*)d_ws;
  size_t off = 0;
  auto alloc = [&](size_t bytes) -> void* {
    void* p = ws + off;
    off = (off + bytes + 255) & ~(size_t)255;
    return p;
  };
  u64* keys     = (u64*)alloc((size_t)BATCH * NANCH * 8);
  u32* hist     = (u32*)alloc((size_t)BATCH * 256 * 4);
  float* selbox = (float*)alloc((size_t)BATCH * MAXC * 4 * 4);
  float* offbox = (float*)alloc((size_t)BATCH * MAXC * 4 * 4);
  float* selconf= (float*)alloc((size_t)BATCH * MAXC * 4);
  float* selcls = (float*)alloc((size_t)BATCH * MAXC * 4);
  u32* selvalid = (u32*)alloc((size_t)BATCH * MAXC * 4);
  u64* dt       = (u64*)alloc((size_t)BATCH * MAXC * 16 * 8);
  (void)ws_size; (void)in_sizes; (void)n_in; (void)out_size;

  hipMemsetAsync(hist, 0, (size_t)BATCH * 256 * 4, stream);

  int k1_blocks = (BATCH * APT + 255) / 256;   // 394
  k1_score<<<k1_blocks, 256, 0, stream>>>(pred, keys, hist);
  k2_select<<<BATCH, 1024, 0, stream>>>(pred, keys, hist, selbox, offbox,
                                        selconf, selcls, selvalid);
  k3_dt<<<(BATCH * MAXC) / 4, 256, 0, stream>>>((const float4*)offbox, dt);
  k4_jacobi<<<BATCH, 1024, 0, stream>>>(dt, selvalid, selbox, selconf,
                                        selcls, out);
}